// Round 2
// baseline (279.353 us; speedup 1.0000x reference)
//
#include <hip/hip_runtime.h>

#define HW 36864            // 192*192
#define HDIM 192
#define NUNITS 8192         // 1024 windows * 8 heads
#define UPB 4               // units per block

__device__ __forceinline__ unsigned pack_bf16(float a, float b) {
    unsigned ua = (__float_as_uint(a) + 0x8000u) >> 16;
    unsigned ub = (__float_as_uint(b) + 0x8000u) & 0xffff0000u;
    return ua | ub;
}
__device__ __forceinline__ float bf_lo(unsigned u) { return __uint_as_float(u << 16); }
__device__ __forceinline__ float bf_hi(unsigned u) { return __uint_as_float(u & 0xffff0000u); }

__global__ __launch_bounds__(256, 5)
void attn_scatter(const float* __restrict__ x,
                  const float* __restrict__ fc,   // (8,8,2) cos/sin
                  const float* __restrict__ wgt,  // (192,192)
                  float* __restrict__ out)        // (576,192,192) pre-zeroed
{
    const int unit = threadIdx.x >> 6;
    const int lane = threadIdx.x & 63;
    const int gid  = blockIdx.x * UPB + unit;   // 0..8191
    const int head = gid & 7;
    const int wi   = gid >> 3;
    const int g    = wi & 3;
    const int iw   = (wi >> 2) & 15;
    const int ih   = wi >> 6;

    const int r   = lane >> 3;
    const int col = lane & 7;

    __shared__ unsigned kbuf[UPB * 64 * 12];  // bf16-pair rows, 12 uints/row
    __shared__ unsigned vbuf[UPB * 64 * 12];
    __shared__ float frs[64];
    __shared__ float fis[64];

    if (threadIdx.x < 64) {
        float2 t = ((const float2*)fc)[threadIdx.x];
        frs[threadIdx.x] = t.x;
        fis[threadIdx.x] = t.y;
    }

    const int h0 = ih * 12 + r;
    const int w0 = iw * 12 + col;
    int in_h = h0 + ((g & 1) ? 6 : 0); if (in_h >= HDIM) in_h = 2 * HDIM - 2 - in_h;
    int in_w = w0 + ((g & 2) ? 6 : 0); if (in_w >= HDIM) in_w = 2 * HDIM - 2 - in_w;

    const float* xb = x + (size_t)(head * 24) * HW + in_h * HDIM + in_w;

    float q[24], k[24];
#pragma unroll
    for (int dd = 0; dd < 24; ++dd) {
        q[dd] = xb[(size_t)dd * HW];
        k[dd] = xb[(size_t)dd * HW + (size_t)192 * HW];
    }
    __syncthreads();  // frs/fis ready

    // positional encoding on q, k
#pragma unroll
    for (int p = 0; p < 8; ++p) {
        const float frr = frs[r * 8 + p],   fir = fis[r * 8 + p];
        const float frc = frs[col * 8 + p], fic = fis[col * 8 + p];
        {
            float a = q[3*p], b = q[3*p+1], c3 = q[3*p+2];
            float b2 = a * fir + b * frr;
            q[3*p]   = a * frr - b * fir;
            q[3*p+1] = b2 * frc - c3 * fic;
            q[3*p+2] = b2 * fic + c3 * frc;
        }
        {
            float a = k[3*p], b = k[3*p+1], c3 = k[3*p+2];
            float b2 = a * fir + b * frr;
            k[3*p]   = a * frr - b * fir;
            k[3*p+1] = b2 * frc - c3 * fic;
            k[3*p+2] = b2 * fic + c3 * frc;
        }
    }

    // stage k (post-PE) as packed bf16
    {
        unsigned* kw = &kbuf[(unit * 64 + lane) * 12];
#pragma unroll
        for (int j = 0; j < 12; ++j) kw[j] = pack_bf16(k[2*j], k[2*j+1]);
    }
    // load + stage v as packed bf16
    {
        unsigned* vw = &vbuf[(unit * 64 + lane) * 12];
        const float* xv = xb + (size_t)384 * HW;
#pragma unroll
        for (int j = 0; j < 12; ++j) {
            float a = xv[(size_t)(2*j) * HW];
            float b = xv[(size_t)(2*j+1) * HW];
            vw[j] = pack_bf16(a, b);
        }
    }
    // pre-scale q by 1/sqrt(24)
#pragma unroll
    for (int dd = 0; dd < 24; ++dd) q[dd] *= 0.20412414523193154f;

    __syncthreads();

    float o[24];
#pragma unroll
    for (int dd = 0; dd < 24; ++dd) o[dd] = 0.f;
    float sum = 0.f;

    const unsigned* kbase = &kbuf[unit * 64 * 12];
    const unsigned* vbase = &vbuf[unit * 64 * 12];

#pragma unroll 4
    for (int m = 0; m < 64; ++m) {
        const uint4* kr = (const uint4*)&kbase[m * 12];
        float s = 0.f;
#pragma unroll
        for (int j4 = 0; j4 < 3; ++j4) {
            uint4 a = kr[j4];
            s += q[8*j4+0] * bf_lo(a.x) + q[8*j4+1] * bf_hi(a.x)
               + q[8*j4+2] * bf_lo(a.y) + q[8*j4+3] * bf_hi(a.y)
               + q[8*j4+4] * bf_lo(a.z) + q[8*j4+5] * bf_hi(a.z)
               + q[8*j4+6] * bf_lo(a.w) + q[8*j4+7] * bf_hi(a.w);
        }
        const float p = __expf(s);
        sum += p;
        const uint4* vr = (const uint4*)&vbase[m * 12];
#pragma unroll
        for (int j4 = 0; j4 < 3; ++j4) {
            uint4 b = vr[j4];
            o[8*j4+0] += p * bf_lo(b.x);  o[8*j4+1] += p * bf_hi(b.x);
            o[8*j4+2] += p * bf_lo(b.y);  o[8*j4+3] += p * bf_hi(b.y);
            o[8*j4+4] += p * bf_lo(b.z);  o[8*j4+5] += p * bf_hi(b.z);
            o[8*j4+6] += p * bf_lo(b.w);  o[8*j4+7] += p * bf_hi(b.w);
        }
    }

    // overlap-add scatter
    const int oh = h0 + ((g & 1) ? 6 : 0);
    const int ow = w0 + ((g & 2) ? 6 : 0);
    if (oh < HDIM && ow < HDIM) {
        const float sc = (1.0f / sum) / wgt[oh * HDIM + ow];
        float* ob = out + (size_t)(head * 24) * HW + oh * HDIM + ow;
#pragma unroll
        for (int dd = 0; dd < 24; ++dd)
            atomicAdd(&ob[(size_t)dd * HW], o[dd] * sc);
    }
}

extern "C" void kernel_launch(void* const* d_in, const int* in_sizes, int n_in,
                              void* d_out, int out_size, void* d_ws, size_t ws_size,
                              hipStream_t stream) {
    const float* x   = (const float*)d_in[0];
    const float* fc  = (const float*)d_in[1];
    const float* wgt = (const float*)d_in[2];
    float* out = (float*)d_out;

    hipMemsetAsync(out, 0, (size_t)out_size * sizeof(float), stream);
    attn_scatter<<<NUNITS / UPB, 256, 0, stream>>>(x, fc, wgt, out);
}

// Round 4
// 261.718 us; speedup vs baseline: 1.0674x; 1.0674x over previous
//
#include <hip/hip_runtime.h>

#define HW 36864            // 192*192
#define HDIM 192
#define NUNITS 8192         // 1024 windows * 8 heads
#define UPB 4               // units per block

typedef __fp16 h2 __attribute__((ext_vector_type(2)));   // matches cvt_pkrtz return type

static __device__ __forceinline__ h2 pk2(float a, float b) {
    return __builtin_amdgcn_cvt_pkrtz(a, b);   // v_cvt_pkrtz_f16_f32
}
static __device__ __forceinline__ unsigned h2u(h2 x) {
    union { h2 h; unsigned u; } c; c.h = x; return c.u;
}
static __device__ __forceinline__ h2 u2h(unsigned x) {
    union { unsigned u; h2 h; } c; c.u = x; return c.h;
}

__global__ __launch_bounds__(256, 6)
void attn_scatter(const float* __restrict__ x,
                  const float* __restrict__ fc,   // (8,8,2) cos/sin
                  const float* __restrict__ wgt,  // (192,192)
                  float* __restrict__ out)        // (576,192,192) pre-zeroed
{
    const int unit = threadIdx.x >> 6;
    const int lane = threadIdx.x & 63;
    const int gid  = blockIdx.x * UPB + unit;   // 0..8191
    const int head = gid & 7;
    const int wi   = gid >> 3;
    const int g    = wi & 3;
    const int iw   = (wi >> 2) & 15;
    const int ih   = wi >> 6;

    const int r   = lane >> 3;
    const int col = lane & 7;

    __shared__ unsigned kbuf[UPB * 64 * 12];  // f16-pair rows, 12 uints/row
    __shared__ unsigned vbuf[UPB * 64 * 12];
    __shared__ float frs[64];
    __shared__ float fis[64];

    if (threadIdx.x < 64) {
        float2 t = ((const float2*)fc)[threadIdx.x];
        frs[threadIdx.x] = t.x;
        fis[threadIdx.x] = t.y;
    }

    const int h0 = ih * 12 + r;
    const int w0 = iw * 12 + col;
    int in_h = h0 + ((g & 1) ? 6 : 0); if (in_h >= HDIM) in_h = 2 * HDIM - 2 - in_h;
    int in_w = w0 + ((g & 2) ? 6 : 0); if (in_w >= HDIM) in_w = 2 * HDIM - 2 - in_w;

    const float* xb = x + (size_t)(head * 24) * HW + in_h * HDIM + in_w;

    float q[24], k[24];
#pragma unroll
    for (int dd = 0; dd < 24; ++dd) {
        q[dd] = xb[(size_t)dd * HW];
        k[dd] = xb[(size_t)dd * HW + (size_t)192 * HW];
    }
    __syncthreads();  // frs/fis ready

    // positional encoding on q, k (fp32)
#pragma unroll
    for (int p = 0; p < 8; ++p) {
        const float frr = frs[r * 8 + p],   fir = fis[r * 8 + p];
        const float frc = frs[col * 8 + p], fic = fis[col * 8 + p];
        {
            float a = q[3*p], b = q[3*p+1], c3 = q[3*p+2];
            float b2 = a * fir + b * frr;
            q[3*p]   = a * frr - b * fir;
            q[3*p+1] = b2 * frc - c3 * fic;
            q[3*p+2] = b2 * fic + c3 * frc;
        }
        {
            float a = k[3*p], b = k[3*p+1], c3 = k[3*p+2];
            float b2 = a * fir + b * frr;
            k[3*p]   = a * frr - b * fir;
            k[3*p+1] = b2 * frc - c3 * fic;
            k[3*p+2] = b2 * fic + c3 * frc;
        }
    }

    // stage k (post-PE) as packed f16 pairs
    {
        unsigned* kw = &kbuf[(unit * 64 + lane) * 12];
#pragma unroll
        for (int j = 0; j < 12; ++j) kw[j] = h2u(pk2(k[2*j], k[2*j+1]));
    }
    // load + stage v as packed f16 pairs
    {
        unsigned* vw = &vbuf[(unit * 64 + lane) * 12];
        const float* xv = xb + (size_t)384 * HW;
#pragma unroll
        for (int j = 0; j < 12; ++j)
            vw[j] = h2u(pk2(xv[(size_t)(2*j) * HW], xv[(size_t)(2*j+1) * HW]));
    }

    // q -> f16 pairs, pre-scaled by 1/sqrt(24)
    h2 qh[12];
#pragma unroll
    for (int j = 0; j < 12; ++j)
        qh[j] = pk2(q[2*j] * 0.20412414523193154f, q[2*j+1] * 0.20412414523193154f);

    __syncthreads();

    float sum = 0.f;
    h2 o2[12];
#pragma unroll
    for (int j = 0; j < 12; ++j) { o2[j][0] = (__fp16)0.0f; o2[j][1] = (__fp16)0.0f; }

    const unsigned* kbase = &kbuf[unit * 64 * 12];
    const unsigned* vbase = &vbuf[unit * 64 * 12];

#pragma unroll 4
    for (int m = 0; m < 64; ++m) {
        unsigned kk[12];
        *(uint4*)&kk[0] = ((const uint4*)&kbase[m * 12])[0];
        *(uint4*)&kk[4] = ((const uint4*)&kbase[m * 12])[1];
        *(uint4*)&kk[8] = ((const uint4*)&kbase[m * 12])[2];

        // 4 independent dot chains (3-deep each), v_dot2_f32_f16
        float d0 = __builtin_amdgcn_fdot2(u2h(kk[0]), qh[0], 0.f, false);
        float d1 = __builtin_amdgcn_fdot2(u2h(kk[1]), qh[1], 0.f, false);
        float d2 = __builtin_amdgcn_fdot2(u2h(kk[2]), qh[2], 0.f, false);
        float d3 = __builtin_amdgcn_fdot2(u2h(kk[3]), qh[3], 0.f, false);
        d0 = __builtin_amdgcn_fdot2(u2h(kk[4]),  qh[4],  d0, false);
        d1 = __builtin_amdgcn_fdot2(u2h(kk[5]),  qh[5],  d1, false);
        d2 = __builtin_amdgcn_fdot2(u2h(kk[6]),  qh[6],  d2, false);
        d3 = __builtin_amdgcn_fdot2(u2h(kk[7]),  qh[7],  d3, false);
        d0 = __builtin_amdgcn_fdot2(u2h(kk[8]),  qh[8],  d0, false);
        d1 = __builtin_amdgcn_fdot2(u2h(kk[9]),  qh[9],  d1, false);
        d2 = __builtin_amdgcn_fdot2(u2h(kk[10]), qh[10], d2, false);
        d3 = __builtin_amdgcn_fdot2(u2h(kk[11]), qh[11], d3, false);
        const float s = (d0 + d1) + (d2 + d3);

        const float p = __expf(s);
        sum += p;
        const h2 p2 = pk2(p, p);

        unsigned vv[12];
        *(uint4*)&vv[0] = ((const uint4*)&vbase[m * 12])[0];
        *(uint4*)&vv[4] = ((const uint4*)&vbase[m * 12])[1];
        *(uint4*)&vv[8] = ((const uint4*)&vbase[m * 12])[2];
#pragma unroll
        for (int j = 0; j < 12; ++j)
            o2[j] += p2 * u2h(vv[j]);          // v_pk_fma_f16
    }

    // overlap-add scatter
    const int oh = h0 + ((g & 1) ? 6 : 0);
    const int ow = w0 + ((g & 2) ? 6 : 0);
    if (oh < HDIM && ow < HDIM) {
        const float sc = (1.0f / sum) / wgt[oh * HDIM + ow];
        float* ob = out + (size_t)(head * 24) * HW + oh * HDIM + ow;
#pragma unroll
        for (int j = 0; j < 12; ++j) {
            atomicAdd(&ob[(size_t)(2*j)     * HW], (float)o2[j][0] * sc);
            atomicAdd(&ob[(size_t)(2*j + 1) * HW], (float)o2[j][1] * sc);
        }
    }
}

extern "C" void kernel_launch(void* const* d_in, const int* in_sizes, int n_in,
                              void* d_out, int out_size, void* d_ws, size_t ws_size,
                              hipStream_t stream) {
    const float* x   = (const float*)d_in[0];
    const float* fc  = (const float*)d_in[1];
    const float* wgt = (const float*)d_in[2];
    float* out = (float*)d_out;

    (void)hipMemsetAsync(out, 0, (size_t)out_size * sizeof(float), stream);
    attn_scatter<<<NUNITS / UPB, 256, 0, stream>>>(x, fc, wgt, out);
}